// Round 1
// baseline (337.456 us; speedup 1.0000x reference)
//
#include <hip/hip_runtime.h>

#define BB 4
#define CC 96
#define LL 32
#define HH 56
#define WW 56
#define HW (HH * WW)
#define KD 16

// ---------------------------------------------------------------------------
// Pass 1: fused causal conv along W then H, per (b,c,l) 56x56 slice.
// grid.x = B*C*L/4, 256 threads; each 64-lane wave owns one slice.
// All 4 slices in a block share (b,c) (4 consecutive l), so kernels are shared.
// ---------------------------------------------------------------------------
__global__ __launch_bounds__(256) void conv_wh(const float* __restrict__ x,
                                               const float* __restrict__ wconv,
                                               const float* __restrict__ hconv,
                                               float* __restrict__ out) {
    __shared__ float sl[4][HH][WW + 1];   // +1 pad: odd stride -> no conflicts
    __shared__ float wk[WW];
    __shared__ float hk[HH];

    const int tid  = threadIdx.x;
    const int wv   = tid >> 6;
    const int lane = tid & 63;
    const int slice0 = blockIdx.x * 4;                 // 4 slices, same (b,c)
    const int c      = (slice0 / LL) % CC;

    if (tid < WW)                      wk[tid]      = wconv[c * WW + tid];
    else if (tid >= 64 && tid < 64+HH) hk[tid - 64] = hconv[c * HH + (tid - 64)];

    // cooperative coalesced load: each wave loads its slice (3136 = 49*64)
    const size_t base = (size_t)(slice0 + wv) * HW;
    #pragma unroll
    for (int i = 0; i < HW / 64; ++i) {
        int m = i * 64 + lane;
        sl[wv][m / WW][m % WW] = x[base + m];
    }
    __syncthreads();

    float xr[HH], acc[HH];

    // ---- W pass: lane = row h ----
    if (lane < HH) {
        #pragma unroll
        for (int j = 0; j < WW; ++j) xr[j] = sl[wv][lane][j];
        #pragma unroll
        for (int j = 0; j < WW; ++j) acc[j] = 0.f;
        #pragma unroll
        for (int d = 0; d < WW; ++d) {
            const float kd = wk[d];                    // wave-uniform broadcast
            #pragma unroll
            for (int w = d; w < WW; ++w)
                acc[w] = fmaf(kd, xr[w - d], acc[w]);
        }
        #pragma unroll
        for (int j = 0; j < WW; ++j) sl[wv][lane][j] = acc[j];
    }
    __syncthreads();

    // ---- H pass: lane = column w ----
    if (lane < WW) {
        #pragma unroll
        for (int h = 0; h < HH; ++h) xr[h] = sl[wv][h][lane];
        #pragma unroll
        for (int h = 0; h < HH; ++h) acc[h] = 0.f;
        #pragma unroll
        for (int d = 0; d < HH; ++d) {
            const float kd = hk[d];
            #pragma unroll
            for (int h = d; h < HH; ++h)
                acc[h] = fmaf(kd, xr[h - d], acc[h]);
        }
        #pragma unroll
        for (int h = 0; h < HH; ++h)
            out[base + (size_t)h * WW + lane] = acc[h];
    }
}

// ---------------------------------------------------------------------------
// Pass 2: causal conv along L, in-place on out. One thread per (b,c,h,w)
// column; reads all 32 before writing -> in-place is race-free.
// grid = (ceil(HW/256), B*C). Length kernel rebuilt per block (cheap).
// ---------------------------------------------------------------------------
__global__ __launch_bounds__(256) void conv_l(float* __restrict__ y,
                                              const float* __restrict__ k0,
                                              const float* __restrict__ k1,
                                              const float* __restrict__ decay) {
    __shared__ float kl[LL];
    __shared__ float s_norm;

    const int tid = threadIdx.x;
    const int bc  = blockIdx.y;             // b*C + c
    const int c   = bc % CC;

    if (tid < LL) {
        float v;
        const float dec = decay[c];
        if (tid < KD) {
            // part 0: kernel0 * decay^(NUM_SCALES-1) = * decay^1
            v = k0[c * KD + tid] * dec;
        } else {
            // part 1: linear interp (scale=2, align_corners=False) of kernel1,
            // first 16 outputs; * decay^0
            const int   i    = tid - KD;
            const float src  = fmaxf((i + 0.5f) * 0.5f - 0.5f, 0.f);
            const int   lo   = (int)floorf(src);
            const float frac = src - (float)lo;
            const int   hi   = min(lo + 1, KD - 1);
            v = k1[c * KD + lo] * (1.f - frac) + k1[c * KD + hi] * frac;
        }
        kl[tid] = v;
    }
    __syncthreads();
    if (tid == 0) {
        float s = 0.f;
        for (int i = 0; i < LL; ++i) s += kl[i] * kl[i];
        s_norm = sqrtf(s);
    }
    __syncthreads();

    const float inv = 1.0f / s_norm;
    float kr[LL];
    #pragma unroll
    for (int i = 0; i < LL; ++i) kr[i] = kl[i] * inv;

    const int pos = blockIdx.x * 256 + tid;
    if (pos >= HW) return;

    float* col = y + (size_t)bc * LL * HW + pos;
    float xin[LL];
    #pragma unroll
    for (int l = 0; l < LL; ++l) xin[l] = col[(size_t)l * HW];

    // in-place causal conv, descending l: xin[j<l] still original when used
    #pragma unroll
    for (int l = LL - 1; l >= 0; --l) {
        float t = 0.f;
        #pragma unroll
        for (int j = 0; j <= l; ++j)
            t = fmaf(kr[l - j], xin[j], t);
        xin[l] = t;
    }
    #pragma unroll
    for (int l = 0; l < LL; ++l) col[(size_t)l * HW] = xin[l];
}

// ---------------------------------------------------------------------------
extern "C" void kernel_launch(void* const* d_in, const int* in_sizes, int n_in,
                              void* d_out, int out_size, void* d_ws, size_t ws_size,
                              hipStream_t stream) {
    const float* x     = (const float*)d_in[0];
    const float* wconv = (const float*)d_in[1];
    const float* hconv = (const float*)d_in[2];
    const float* k0    = (const float*)d_in[3];
    const float* k1    = (const float*)d_in[4];
    const float* dec   = (const float*)d_in[5];
    float*       out   = (float*)d_out;

    conv_wh<<<dim3(BB * CC * LL / 4), 256, 0, stream>>>(x, wconv, hconv, out);
    conv_l<<<dim3((HW + 255) / 256, BB * CC), 256, 0, stream>>>(out, k0, k1, dec);
}